// Round 8
// baseline (311.831 us; speedup 1.0000x reference)
//
#include <hip/hip_runtime.h>
#include <cstddef>

typedef __attribute__((ext_vector_type(8))) short short8;
typedef __attribute__((ext_vector_type(4))) float floatx4;

// ---------------------------------------------------------------- bf16 utils
__device__ __forceinline__ unsigned short f2bf(float f) {
  union { float f; unsigned u; } v; v.f = f;
  const unsigned r = v.u + 0x7fffu + ((v.u >> 16) & 1u);  // RNE
  return (unsigned short)(r >> 16);
}

// ---------------------------------------------------------------- reductions
__device__ __forceinline__ float block_reduce_sum(float v, float* sm) {
#pragma unroll
  for (int off = 32; off > 0; off >>= 1) v += __shfl_down(v, off, 64);
  const int lane = threadIdx.x & 63, wid = threadIdx.x >> 6;
  __syncthreads();
  if (lane == 0) sm[wid] = v;
  __syncthreads();
  if (threadIdx.x == 0) {
    float t = 0.f;
    const int nw = (blockDim.x + 63) >> 6;
    for (int i = 0; i < nw; ++i) t += sm[i];
    sm[0] = t;
  }
  __syncthreads();
  return sm[0];
}

// ---------------------------------------------------------------- ternarize
// Grid-parallel 3-phase TWN over all 4 weight tensors at once.
// red[t*4+0]=sum|w|, red[t*4+1]=masked count, red[t*4+2]=masked sum|w|.
__device__ __forceinline__ void tsel(int t, const float* w0, const float* w1,
                                     const float* w2, const float* w3, int n0,
                                     int n1, int n2, int n3,
                                     const float*& w, int& n) {
  w = (t == 0) ? w0 : (t == 1) ? w1 : (t == 2) ? w2 : w3;
  n = (t == 0) ? n0 : (t == 1) ? n1 : (t == 2) ? n2 : n3;
}

__global__ __launch_bounds__(256) void tern_phase1(
    const float* w0, const float* w1, const float* w2, const float* w3,
    int n0, int n1, int n2, int n3, float* __restrict__ red) {
  __shared__ float sm[8];
  const float* w; int n;
  tsel(blockIdx.y, w0, w1, w2, w3, n0, n1, n2, n3, w, n);
  if ((int)blockIdx.x * 256 >= n) return;
  const int i = blockIdx.x * 256 + threadIdx.x;
  float s = (i < n) ? fabsf(w[i]) : 0.f;
  s = block_reduce_sum(s, sm);
  if (threadIdx.x == 0) atomicAdd(&red[blockIdx.y * 4 + 0], s);
}

__global__ __launch_bounds__(256) void tern_phase2(
    const float* w0, const float* w1, const float* w2, const float* w3,
    int n0, int n1, int n2, int n3, float* __restrict__ red) {
  __shared__ float sm[8];
  const float* w; int n;
  tsel(blockIdx.y, w0, w1, w2, w3, n0, n1, n2, n3, w, n);
  if ((int)blockIdx.x * 256 >= n) return;
  const float delta = 0.7f * red[blockIdx.y * 4 + 0] / (float)n;
  const int i = blockIdx.x * 256 + threadIdx.x;
  float c = 0.f, a = 0.f;
  if (i < n) {
    const float v = fabsf(w[i]);
    if (v > delta) { c = 1.f; a = v; }
  }
  c = block_reduce_sum(c, sm);
  a = block_reduce_sum(a, sm);
  if (threadIdx.x == 0) {
    atomicAdd(&red[blockIdx.y * 4 + 1], c);
    atomicAdd(&red[blockIdx.y * 4 + 2], a);
  }
}

// Materialize fp32 q (+/-alpha / 0) for wl only (linear layer).
__global__ __launch_bounds__(256) void tern_phase3(
    const float* __restrict__ w, int n, float* __restrict__ q,
    const float* __restrict__ red) {
  const float delta = 0.7f * red[12] / (float)n;
  const float alpha = red[14] / fmaxf(red[13], 1.f);
  const int i = blockIdx.x * 256 + threadIdx.x;
  if (i < n) {
    const float wi = w[i];
    q[i] = (fabsf(wi) > delta) ? copysignf(alpha, wi) : 0.f;
  }
}

// ---------------------------------------------------------------- BN fold
__global__ void bnfold_all(
    const float* g1, const float* b1, const float* m1, const float* v1,
    const float* g2, const float* b2, const float* m2, const float* v2,
    const float* g3, const float* b3, const float* m3, const float* v3,
    float* s1, float* bb1, float* s2, float* bb2, float* s3, float* bb3,
    const float* __restrict__ red) {
  const int i = threadIdx.x;
  if (i < 32) {
    const float inv = g1[i] / sqrtf(v1[i] + 1e-5f);
    const float a = red[2] / fmaxf(red[1], 1.f);
    s1[i] = a * inv; bb1[i] = b1[i] - m1[i] * inv;
  } else if (i < 96) {
    const int c = i - 32;
    const float inv = g2[c] / sqrtf(v2[c] + 1e-5f);
    const float a = red[6] / fmaxf(red[5], 1.f);
    s2[c] = a * inv; bb2[c] = b2[c] - m2[c] * inv;
  } else if (i < 224) {
    const int c = i - 96;
    const float inv = g3[c] / sqrtf(v3[c] + 1e-5f);
    const float a = red[10] / fmaxf(red[9], 1.f);
    s3[c] = a * inv; bb3[c] = b3[c] - m3[c] * inv;
  }
}

// ---------------------------------------------------------------- weight pack
// conv2/3: OIHW fp32 -> sign bf16 (+1/-1/0), k=(kh*3+kw)*CIN+ic, stored
// ((k>>3)*COUT+n)*8+(k&7) so a lane's B-frag is one 16B global load.
template <int CIN, int COUT>
__global__ void pack_weights(const float* __restrict__ w,
                             const float* __restrict__ red_t,
                             unsigned short* __restrict__ bp) {
  constexpr int K = CIN * 9;
  const float delta = 0.7f * red_t[0] / (float)(K * COUT);
  const int idx = blockIdx.x * 256 + threadIdx.x;
  if (idx >= K * COUT) return;
  const int k = idx / COUT, n = idx % COUT;
  const int tap = k / CIN, ic = k % CIN;
  const int kh = tap / 3, kw = tap % 3;
  const float v = w[(((size_t)n * CIN + ic) * 3 + kh) * 3 + kw];
  const unsigned short sgn = (v > delta) ? 0x3F80u : (v < -delta ? 0xBF80u : 0u);
  bp[((size_t)(k >> 3) * COUT + n) * 8 + (k & 7)] = sgn;
}

// conv1: OIHW [32][3][3][3] -> tap-major fp32 signs q1t[tap][oc]
__global__ void pack_w1(const float* __restrict__ w,
                        const float* __restrict__ red,
                        float* __restrict__ q1t) {
  const int idx = threadIdx.x + blockIdx.x * 256;
  if (idx >= 864) return;
  const float delta = 0.7f * red[0] / 864.f;
  const int tap = idx / 32, oc = idx % 32;
  const int ic = tap / 9, kh = (tap % 9) / 3, kw = tap % 3;
  const float v = w[((oc * 3 + ic) * 3 + kh) * 3 + kw];
  q1t[idx] = (v > delta) ? 1.f : (v < -delta ? -1.f : 0.f);
}

// ---------------------------------------------------------------- conv1 v2
__global__ __launch_bounds__(256) void conv1_v2(
    const float* __restrict__ x, const float* __restrict__ q1t,
    const float* __restrict__ scale, const float* __restrict__ bias,
    unsigned short* __restrict__ y) {
  __shared__ float xs[15 * 225];  // [ic*5 + dr][slot], slot = iw+1
  const int n = blockIdx.y;
  const int oh0 = blockIdx.x * 2;
  const int t = threadIdx.x;
  const int ih_base = oh0 * 2 - 1;
  for (int idx = t; idx < 15 * 225; idx += 256) {
    const int row = idx / 225, s = idx % 225;
    const int ic = row / 5, dr = row % 5;
    const int ih = ih_base + dr, iw = s - 1;
    float v = 0.f;
    if ((unsigned)ih < 224u && (unsigned)iw < 224u)
      v = x[((size_t)n * 3 + ic) * 50176 + (size_t)ih * 224 + iw];
    xs[idx] = v;
  }
  __syncthreads();
  if (t >= 224) return;
  const int r = t / 112, ow = t % 112;
  float acc[32];
#pragma unroll
  for (int j = 0; j < 32; ++j) acc[j] = 0.f;
#pragma unroll
  for (int ic = 0; ic < 3; ++ic)
#pragma unroll
    for (int kh = 0; kh < 3; ++kh) {
      const float* xr = &xs[(ic * 5 + r * 2 + kh) * 225 + 2 * ow];
      const float xv0 = xr[0], xv1 = xr[1], xv2 = xr[2];
#pragma unroll
      for (int kw = 0; kw < 3; ++kw) {
        const float xv = (kw == 0) ? xv0 : (kw == 1) ? xv1 : xv2;
        const float* wrow = &q1t[(ic * 9 + kh * 3 + kw) * 32];
#pragma unroll
        for (int j = 0; j < 32; ++j) acc[j] += xv * wrow[j];
      }
    }
  const int oh = oh0 + r;
  unsigned pk[16];
#pragma unroll
  for (int h = 0; h < 16; ++h) {
    const float a0 = fmaxf(acc[2 * h] * scale[2 * h] + bias[2 * h], 0.f);
    const float a1 = fmaxf(acc[2 * h + 1] * scale[2 * h + 1] + bias[2 * h + 1], 0.f);
    pk[h] = (unsigned)f2bf(a0) | ((unsigned)f2bf(a1) << 16);
  }
  unsigned short* dst = y + (((size_t)n * 112 + oh) * 112 + ow) * 32;
#pragma unroll
  for (int v = 0; v < 4; ++v)
    *(uint4*)(dst + v * 8) = make_uint4(pk[4 * v], pk[4 * v + 1],
                                        pk[4 * v + 2], pk[4 * v + 3]);
}

// ---------------------------------------------------------------- fused conv2+conv3+pool
// Block = one 8x8 conv3-output tile of one image (grid 49 x 64; 56%8==0).
// act2 NEVER touches global memory:
//   stage 19x19x32 act1 patch in LDS (seg-major; A-frag = conflict-free
//   ds_read_b128) -> per 32-ch half: conv2 via MFMA (M=17x17=289 px padded to
//   19 frags, masked) -> BN2+ReLU+bf16 into c2p LDS buffer in conv3's
//   seg-major parity-split layout, TRUE ZERO for out-of-image conv2 coords
//   (BN bias must not leak into padding) -> conv3 9 taps from LDS.
// conv3 waves split N (wave owns 32 ch, all 4 M-frags) to minimize B traffic.
// Pool: in-register quad reduce -> LDS -> one atomicAdd per channel.
__global__ __launch_bounds__(256) void conv23_fused(
    const unsigned short* __restrict__ act1,
    const unsigned short* __restrict__ bp2,
    const unsigned short* __restrict__ bp3,
    const float* __restrict__ s2, const float* __restrict__ bb2,
    const float* __restrict__ s3, const float* __restrict__ bb3,
    float* __restrict__ pooled) {
  __shared__ unsigned short a1p[4 * 19 * 19 * 8];  // 23104 B
  __shared__ unsigned short c2p[4 * 17 * 18 * 8];  // 19584 B
  const int t = threadIdx.x;
  const int img = blockIdx.y;
  const int ty = blockIdx.x / 7, tx = blockIdx.x % 7;
  const int o3h0 = ty * 8, o3w0 = tx * 8;
  const int wave = t >> 6, lane = t & 63, quad = lane >> 4, l16 = lane & 15;

  // ---- stage act1 patch: 19x19 px x 4 ch-segs of 16B
  {
    const int h0 = o3h0 * 2 - 2, w0 = o3w0 * 2 - 2;
    for (int c = t; c < 19 * 19 * 4; c += 256) {
      const int pix = c >> 2, seg = c & 3;
      const int pi = pix / 19, pj = pix % 19;
      const int ih = h0 + pi, iw = w0 + pj;
      uint4 v = make_uint4(0u, 0u, 0u, 0u);
      if ((unsigned)ih < 112u && (unsigned)iw < 112u)
        v = *(const uint4*)(act1 + (((size_t)img * 112 + ih) * 112 + iw) * 32 +
                            seg * 8);
      *(uint4*)(&a1p[((seg * 19 + pi) * 19 + pj) * 8]) = v;
    }
  }

  // conv2 A base offsets: wave handles m-frags {wave, wave+4, ...} (19 total)
  int aoff[5];
#pragma unroll
  for (int i = 0; i < 5; ++i) {
    int px = (wave + 4 * i) * 16 + l16;
    px = px < 289 ? px : 288;  // clamp (masked on write)
    const int pi = px / 17, pj = px % 17;
    aoff[i] = ((quad * 19 + pi) * 19 + pj) * 8;
  }
  // conv3 A base offsets: wave owns all 4 m-frags
  int a3off[4];
#pragma unroll
  for (int mf = 0; mf < 4; ++mf) {
    const int px = mf * 16 + l16;
    a3off[mf] = ((quad * 17 + (px >> 3) * 2) * 18 + (px & 7)) * 8;
  }

  floatx4 acc3[4][2];
#pragma unroll
  for (int mf = 0; mf < 4; ++mf)
#pragma unroll
    for (int nf = 0; nf < 2; ++nf) acc3[mf][nf] = (floatx4){0.f, 0.f, 0.f, 0.f};

  __syncthreads();  // act1 patch ready

#pragma unroll
  for (int h = 0; h < 2; ++h) {
    // ---- conv2: 9 taps, full CIN=32 per MFMA (K=32)
    floatx4 acc2[5][2];
#pragma unroll
    for (int i = 0; i < 5; ++i) {
      acc2[i][0] = (floatx4){0.f, 0.f, 0.f, 0.f};
      acc2[i][1] = (floatx4){0.f, 0.f, 0.f, 0.f};
    }
#pragma unroll
    for (int tap = 0; tap < 9; ++tap) {
      const int kh = tap / 3, kw = tap % 3;
      const short8 b0 = *(const short8*)(
          bp2 + ((size_t)(tap * 4 + quad) * 64 + h * 32 + l16) * 8);
      const short8 b1 = *(const short8*)(
          bp2 + ((size_t)(tap * 4 + quad) * 64 + h * 32 + 16 + l16) * 8);
      const int toff = (kh * 19 + kw) * 8;
#pragma unroll
      for (int i = 0; i < 5; ++i)
        if (wave + 4 * i < 19) {
          const short8 a = *(const short8*)(&a1p[aoff[i] + toff]);
          acc2[i][0] = __builtin_amdgcn_mfma_f32_16x16x32_bf16(a, b0,
                                                              acc2[i][0], 0, 0, 0);
          acc2[i][1] = __builtin_amdgcn_mfma_f32_16x16x32_bf16(a, b1,
                                                              acc2[i][1], 0, 0, 0);
        }
    }
    if (h) __syncthreads();  // conv3 reads of previous half done
    // ---- BN2+ReLU -> c2p (C layout: row px = mf*16+quad*4+r, col ch = l16)
#pragma unroll
    for (int nf = 0; nf < 2; ++nf) {
      const int ch = nf * 16 + l16;  // channel within this 32-ch half
      const float sc = s2[h * 32 + ch], bs = bb2[h * 32 + ch];
#pragma unroll
      for (int i = 0; i < 5; ++i) {
        const int mf = wave + 4 * i;
        if (mf < 19) {
#pragma unroll
          for (int r = 0; r < 4; ++r) {
            const int px2 = mf * 16 + quad * 4 + r;
            if (px2 < 289) {
              const int pi = px2 / 17, pj = px2 % 17;
              const bool inb = (unsigned)(o3h0 * 2 - 1 + pi) < 112u &&
                               (unsigned)(o3w0 * 2 - 1 + pj) < 112u;
              const float v =
                  inb ? fmaxf(acc2[i][nf][r] * sc + bs, 0.f) : 0.f;
              const int slot = (pj >> 1) + (pj & 1) * 9;  // parity split
              c2p[(((ch >> 3) * 17 + pi) * 18 + slot) * 8 + (ch & 7)] = f2bf(v);
            }
          }
        }
      }
    }
    __syncthreads();  // c2p visible
    // ---- conv3: 9 taps over this 32-ch half; wave owns ch wave*32..+31
#pragma unroll
    for (int tap = 0; tap < 9; ++tap) {
      const int kh = tap / 3, kw = tap % 3;
      const int kg = tap * 8 + h * 4 + quad;
      const short8 b0 = *(const short8*)(
          bp3 + ((size_t)kg * 128 + wave * 32 + l16) * 8);
      const short8 b1 = *(const short8*)(
          bp3 + ((size_t)kg * 128 + wave * 32 + 16 + l16) * 8);
      const int toff = (kh * 18 + (kw >> 1) + (kw & 1) * 9) * 8;
#pragma unroll
      for (int mf = 0; mf < 4; ++mf) {
        const short8 a = *(const short8*)(&c2p[a3off[mf] + toff]);
        acc3[mf][0] = __builtin_amdgcn_mfma_f32_16x16x32_bf16(a, b0,
                                                              acc3[mf][0], 0, 0, 0);
        acc3[mf][1] = __builtin_amdgcn_mfma_f32_16x16x32_bf16(a, b1,
                                                              acc3[mf][1], 0, 0, 0);
      }
    }
  }

  // ---- epilogue: BN3 + ReLU + pool (wave owns disjoint channels)
  float* pbuf = (float*)a1p;  // 128 floats; a1p dead (2 barriers since last read)
#pragma unroll
  for (int nf = 0; nf < 2; ++nf) {
    const int ch = wave * 32 + nf * 16 + l16;
    const float sc = s3[ch], bs = bb3[ch];
    float s = 0.f;
#pragma unroll
    for (int mf = 0; mf < 4; ++mf)
#pragma unroll
      for (int r = 0; r < 4; ++r)
        s += fmaxf(acc3[mf][nf][r] * sc + bs, 0.f);
    s += __shfl_xor(s, 16);
    s += __shfl_xor(s, 32);
    if (lane < 16) pbuf[ch] = s;
  }
  __syncthreads();
  if (t < 128) atomicAdd(&pooled[(size_t)img * 128 + t], pbuf[t]);
}

// ---------------------------------------------------------------- linear
// pooled holds SUMS over 3136 pixels; divide here.
__global__ void linear_kernel(const float* __restrict__ pooled,
                              const float* __restrict__ ql,
                              const float* __restrict__ bl,
                              float* __restrict__ out) {
  const int idx = blockIdx.x * blockDim.x + threadIdx.x;
  if (idx >= 64 * 10) return;
  const int n = idx / 10, o = idx % 10;
  const float* p = pooled + (size_t)n * 128;
  const float* w = ql + (size_t)o * 128;
  float s = 0.f;
#pragma unroll 4
  for (int c = 0; c < 128; ++c) s += p[c] * w[c];
  out[idx] = s * (1.f / 3136.f) + bl[o];
}

// ---------------------------------------------------------------- launch
extern "C" void kernel_launch(void* const* d_in, const int* in_sizes, int n_in,
                              void* d_out, int out_size, void* d_ws,
                              size_t ws_size, hipStream_t stream) {
  const float* x  = (const float*)d_in[0];
  const float* w1 = (const float*)d_in[1];
  const float* g1 = (const float*)d_in[2];
  const float* b1 = (const float*)d_in[3];
  const float* m1 = (const float*)d_in[4];
  const float* v1 = (const float*)d_in[5];
  const float* w2 = (const float*)d_in[6];
  const float* g2 = (const float*)d_in[7];
  const float* b2 = (const float*)d_in[8];
  const float* m2 = (const float*)d_in[9];
  const float* v2 = (const float*)d_in[10];
  const float* w3 = (const float*)d_in[11];
  const float* g3 = (const float*)d_in[12];
  const float* b3 = (const float*)d_in[13];
  const float* m3 = (const float*)d_in[14];
  const float* v3 = (const float*)d_in[15];
  const float* wl = (const float*)d_in[16];
  const float* bl = (const float*)d_in[17];
  float* out = (float*)d_out;

  // ---- workspace layout ----
  float* Wf = (float*)d_ws;
  float* red = Wf;                // 16
  float* pooled = red + 16;       // 8192 (zeroed with red in one memset)
  float* q1t = pooled + 8192;     // 864
  float* ql = q1t + 864;          // 1280
  float* s1 = ql + 1280;  float* bb1 = s1 + 32;
  float* s2 = bb1 + 32;   float* bb2 = s2 + 64;
  float* s3 = bb2 + 64;   float* bb3 = s3 + 128;
  unsigned short* Us = (unsigned short*)(bb3 + 128);
  unsigned short* bp2 = Us;                 // 288*64   = 18432
  unsigned short* bp3 = bp2 + 18432;        // 576*128  = 73728
  unsigned short* act1 = bp3 + 73728;       // 64*12544*32 = 25690112
  // total ~52 MB < ws_size (act2 eliminated by fusion)

  // ---- ternarize (grid-parallel, 3 phases over all 4 tensors) ----
  hipMemsetAsync(red, 0, (16 + 8192) * sizeof(float), stream);
  tern_phase1<<<dim3(288, 4), 256, 0, stream>>>(w1, w2, w3, wl, 864, 18432,
                                                73728, 1280, red);
  tern_phase2<<<dim3(288, 4), 256, 0, stream>>>(w1, w2, w3, wl, 864, 18432,
                                                73728, 1280, red);
  tern_phase3<<<5, 256, 0, stream>>>(wl, 1280, ql, red);

  bnfold_all<<<1, 256, 0, stream>>>(g1, b1, m1, v1, g2, b2, m2, v2, g3, b3,
                                    m3, v3, s1, bb1, s2, bb2, s3, bb3, red);
  pack_w1<<<4, 256, 0, stream>>>(w1, red, q1t);
  pack_weights<32, 64><<<72, 256, 0, stream>>>(w2, red + 4, bp2);
  pack_weights<64, 128><<<288, 256, 0, stream>>>(w3, red + 8, bp3);

  // ---- network ----
  conv1_v2<<<dim3(56, 64), 256, 0, stream>>>(x, q1t, s1, bb1, act1);
  conv23_fused<<<dim3(49, 64), 256, 0, stream>>>(act1, bp2, bp3, s2, bb2, s3,
                                                 bb3, pooled);
  linear_kernel<<<3, 256, 0, stream>>>(pooled, ql, bl, out);
}

// Round 9
// 275.510 us; speedup vs baseline: 1.1318x; 1.1318x over previous
//
#include <hip/hip_runtime.h>
#include <cstddef>

typedef __attribute__((ext_vector_type(8))) short short8;
typedef __attribute__((ext_vector_type(4))) float floatx4;

// ---------------------------------------------------------------- bf16 utils
__device__ __forceinline__ unsigned short f2bf(float f) {
  union { float f; unsigned u; } v; v.f = f;
  const unsigned r = v.u + 0x7fffu + ((v.u >> 16) & 1u);  // RNE
  return (unsigned short)(r >> 16);
}

// ---------------------------------------------------------------- reductions
__device__ __forceinline__ float block_reduce_sum(float v, float* sm) {
#pragma unroll
  for (int off = 32; off > 0; off >>= 1) v += __shfl_down(v, off, 64);
  const int lane = threadIdx.x & 63, wid = threadIdx.x >> 6;
  __syncthreads();
  if (lane == 0) sm[wid] = v;
  __syncthreads();
  if (threadIdx.x == 0) {
    float t = 0.f;
    const int nw = (blockDim.x + 63) >> 6;
    for (int i = 0; i < nw; ++i) t += sm[i];
    sm[0] = t;
  }
  __syncthreads();
  return sm[0];
}

// ---------------------------------------------------------------- ternarize
// red[t*4+0]=sum|w|, red[t*4+1]=masked count, red[t*4+2]=masked sum|w|.
__device__ __forceinline__ void tsel(int t, const float* w0, const float* w1,
                                     const float* w2, const float* w3, int n0,
                                     int n1, int n2, int n3,
                                     const float*& w, int& n) {
  w = (t == 0) ? w0 : (t == 1) ? w1 : (t == 2) ? w2 : w3;
  n = (t == 0) ? n0 : (t == 1) ? n1 : (t == 2) ? n2 : n3;
}

__global__ __launch_bounds__(256) void tern_phase1(
    const float* w0, const float* w1, const float* w2, const float* w3,
    int n0, int n1, int n2, int n3, float* __restrict__ red) {
  __shared__ float sm[8];
  const float* w; int n;
  tsel(blockIdx.y, w0, w1, w2, w3, n0, n1, n2, n3, w, n);
  if ((int)blockIdx.x * 256 >= n) return;
  const int i = blockIdx.x * 256 + threadIdx.x;
  float s = (i < n) ? fabsf(w[i]) : 0.f;
  s = block_reduce_sum(s, sm);
  if (threadIdx.x == 0) atomicAdd(&red[blockIdx.y * 4 + 0], s);
}

__global__ __launch_bounds__(256) void tern_phase2(
    const float* w0, const float* w1, const float* w2, const float* w3,
    int n0, int n1, int n2, int n3, float* __restrict__ red) {
  __shared__ float sm[8];
  const float* w; int n;
  tsel(blockIdx.y, w0, w1, w2, w3, n0, n1, n2, n3, w, n);
  if ((int)blockIdx.x * 256 >= n) return;
  const float delta = 0.7f * red[blockIdx.y * 4 + 0] / (float)n;
  const int i = blockIdx.x * 256 + threadIdx.x;
  float c = 0.f, a = 0.f;
  if (i < n) {
    const float v = fabsf(w[i]);
    if (v > delta) { c = 1.f; a = v; }
  }
  c = block_reduce_sum(c, sm);
  a = block_reduce_sum(a, sm);
  if (threadIdx.x == 0) {
    atomicAdd(&red[blockIdx.y * 4 + 1], c);
    atomicAdd(&red[blockIdx.y * 4 + 2], a);
  }
}

// ---------------------------------------------------------------- prep (merged)
// One kernel for: BN folds (block 0), conv1 sign pack (blocks 1-4),
// wl ternarize-materialize (blocks 5-9), bp2 pack (10-81), bp3 pack (82-369).
__global__ __launch_bounds__(256) void prep_all(
    const float* w1, const float* w2, const float* w3, const float* wl,
    const float* g1, const float* b1, const float* m1, const float* v1,
    const float* g2, const float* b2, const float* m2, const float* v2,
    const float* g3, const float* b3, const float* m3, const float* v3,
    const float* __restrict__ red, float* q1t, float* ql,
    float* s1, float* bb1, float* s2, float* bb2, float* s3, float* bb3,
    unsigned short* bp2, unsigned short* bp3) {
  const int b = blockIdx.x, t = threadIdx.x;
  if (b == 0) {
    if (t < 32) {
      const float inv = g1[t] / sqrtf(v1[t] + 1e-5f);
      const float a = red[2] / fmaxf(red[1], 1.f);
      s1[t] = a * inv; bb1[t] = b1[t] - m1[t] * inv;
    } else if (t < 96) {
      const int c = t - 32;
      const float inv = g2[c] / sqrtf(v2[c] + 1e-5f);
      const float a = red[6] / fmaxf(red[5], 1.f);
      s2[c] = a * inv; bb2[c] = b2[c] - m2[c] * inv;
    } else if (t < 224) {
      const int c = t - 96;
      const float inv = g3[c] / sqrtf(v3[c] + 1e-5f);
      const float a = red[10] / fmaxf(red[9], 1.f);
      s3[c] = a * inv; bb3[c] = b3[c] - m3[c] * inv;
    }
  } else if (b <= 4) {
    const int idx = (b - 1) * 256 + t;  // conv1 signs, tap-major
    if (idx < 864) {
      const float delta = 0.7f * red[0] / 864.f;
      const int tap = idx / 32, oc = idx % 32;
      const int ic = tap / 9, kh = (tap % 9) / 3, kw = tap % 3;
      const float v = w1[((oc * 3 + ic) * 3 + kh) * 3 + kw];
      q1t[idx] = (v > delta) ? 1.f : (v < -delta ? -1.f : 0.f);
    }
  } else if (b <= 9) {
    const int i = (b - 5) * 256 + t;  // wl: fp32 +/-alpha / 0
    if (i < 1280) {
      const float delta = 0.7f * red[12] / 1280.f;
      const float alpha = red[14] / fmaxf(red[13], 1.f);
      const float wi = wl[i];
      ql[i] = (fabsf(wi) > delta) ? copysignf(alpha, wi) : 0.f;
    }
  } else if (b <= 81) {
    const int idx = (b - 10) * 256 + t;  // bp2: CIN=32, COUT=64
    const float delta = 0.7f * red[4] / 18432.f;
    const int k = idx / 64, n = idx % 64;
    const int tap = k / 32, ic = k % 32;
    const int kh = tap / 3, kw = tap % 3;
    const float v = w2[(((size_t)n * 32 + ic) * 3 + kh) * 3 + kw];
    bp2[((size_t)(k >> 3) * 64 + n) * 8 + (k & 7)] =
        (v > delta) ? 0x3F80u : (v < -delta ? 0xBF80u : 0u);
  } else {
    const int idx = (b - 82) * 256 + t;  // bp3: CIN=64, COUT=128
    const float delta = 0.7f * red[8] / 73728.f;
    const int k = idx / 128, n = idx % 128;
    const int tap = k / 64, ic = k % 64;
    const int kh = tap / 3, kw = tap % 3;
    const float v = w3[(((size_t)n * 64 + ic) * 3 + kh) * 3 + kw];
    bp3[((size_t)(k >> 3) * 128 + n) * 8 + (k & 7)] =
        (v > delta) ? 0x3F80u : (v < -delta ? 0xBF80u : 0u);
  }
}

// ---------------------------------------------------------------- conv1 v2
__global__ __launch_bounds__(256) void conv1_v2(
    const float* __restrict__ x, const float* __restrict__ q1t,
    const float* __restrict__ scale, const float* __restrict__ bias,
    unsigned short* __restrict__ y) {
  __shared__ float xs[15 * 225];  // [ic*5 + dr][slot], slot = iw+1
  const int n = blockIdx.y;
  const int oh0 = blockIdx.x * 2;
  const int t = threadIdx.x;
  const int ih_base = oh0 * 2 - 1;
  for (int idx = t; idx < 15 * 225; idx += 256) {
    const int row = idx / 225, s = idx % 225;
    const int ic = row / 5, dr = row % 5;
    const int ih = ih_base + dr, iw = s - 1;
    float v = 0.f;
    if ((unsigned)ih < 224u && (unsigned)iw < 224u)
      v = x[((size_t)n * 3 + ic) * 50176 + (size_t)ih * 224 + iw];
    xs[idx] = v;
  }
  __syncthreads();
  if (t >= 224) return;
  const int r = t / 112, ow = t % 112;
  float acc[32];
#pragma unroll
  for (int j = 0; j < 32; ++j) acc[j] = 0.f;
#pragma unroll
  for (int ic = 0; ic < 3; ++ic)
#pragma unroll
    for (int kh = 0; kh < 3; ++kh) {
      const float* xr = &xs[(ic * 5 + r * 2 + kh) * 225 + 2 * ow];
      const float xv0 = xr[0], xv1 = xr[1], xv2 = xr[2];
#pragma unroll
      for (int kw = 0; kw < 3; ++kw) {
        const float xv = (kw == 0) ? xv0 : (kw == 1) ? xv1 : xv2;
        const float* wrow = &q1t[(ic * 9 + kh * 3 + kw) * 32];
#pragma unroll
        for (int j = 0; j < 32; ++j) acc[j] += xv * wrow[j];
      }
    }
  const int oh = oh0 + r;
  unsigned pk[16];
#pragma unroll
  for (int h = 0; h < 16; ++h) {
    const float a0 = fmaxf(acc[2 * h] * scale[2 * h] + bias[2 * h], 0.f);
    const float a1 = fmaxf(acc[2 * h + 1] * scale[2 * h + 1] + bias[2 * h + 1], 0.f);
    pk[h] = (unsigned)f2bf(a0) | ((unsigned)f2bf(a1) << 16);
  }
  unsigned short* dst = y + (((size_t)n * 112 + oh) * 112 + ow) * 32;
#pragma unroll
  for (int v = 0; v < 4; ++v)
    *(uint4*)(dst + v * 8) = make_uint4(pk[4 * v], pk[4 * v + 1],
                                        pk[4 * v + 2], pk[4 * v + 3]);
}

// ---------------------------------------------------------------- conv2 (halo)
// Block = 8x16 output tile x COUT=64. Patch in LDS once; B frags from global
// (L2-hot) prefetched one tap ahead. 1 barrier per block.
__global__ __launch_bounds__(256) void conv2_halo(
    const unsigned short* __restrict__ xin,
    const unsigned short* __restrict__ bp,
    const float* __restrict__ scale, const float* __restrict__ bias,
    unsigned short* __restrict__ yout) {
  constexpr int PH = 10, PW = 18;
  __shared__ unsigned short patch[4 * PH * PW * 8];
  const int t = threadIdx.x;
  const int img = blockIdx.z;
  const int toh = blockIdx.x / 7, tow = blockIdx.x % 7;
  const int wave = t >> 6, lane = t & 63, quad = lane >> 4, l16 = lane & 15;
  const int oh0 = toh * 8, ow0 = tow * 16;

  for (int c = t; c < PH * PW * 4; c += 256) {
    const int pix = c >> 2, seg = c & 3;
    const int pi = pix / PW, pj = pix % PW;
    const int ih = oh0 - 1 + pi, iw = ow0 - 1 + pj;
    uint4 v = make_uint4(0u, 0u, 0u, 0u);
    if ((unsigned)ih < 112u && (unsigned)iw < 112u)
      v = *(const uint4*)(xin + (((size_t)img * 112 + ih) * 112 + iw) * 32 +
                          seg * 8);
    *(uint4*)(&patch[((seg * PH + pi) * PW + pj) * 8]) = v;
  }

  floatx4 acc[2][4];
#pragma unroll
  for (int mf = 0; mf < 2; ++mf)
#pragma unroll
    for (int nf = 0; nf < 4; ++nf) acc[mf][nf] = (floatx4){0.f, 0.f, 0.f, 0.f};

  short8 bcur[4], bnxt[4];
#pragma unroll
  for (int nf = 0; nf < 4; ++nf)
    bcur[nf] = *(const short8*)(bp + ((size_t)quad * 64 + nf * 16 + l16) * 8);
  __syncthreads();

#pragma unroll
  for (int tap = 0; tap < 9; ++tap) {
    const int kh = tap / 3, kw = tap % 3;
    if (tap + 1 < 9) {
      const int kg = (tap + 1) * 4 + quad;
#pragma unroll
      for (int nf = 0; nf < 4; ++nf)
        bnxt[nf] = *(const short8*)(bp + ((size_t)kg * 64 + nf * 16 + l16) * 8);
    }
#pragma unroll
    for (int mf = 0; mf < 2; ++mf) {
      const int pi = (wave * 2 + mf) + kh;
      const short8 a = *(const short8*)(
          &patch[((quad * PH + pi) * PW + l16 + kw) * 8]);
#pragma unroll
      for (int nf = 0; nf < 4; ++nf)
        acc[mf][nf] = __builtin_amdgcn_mfma_f32_16x16x32_bf16(
            a, bcur[nf], acc[mf][nf], 0, 0, 0);
    }
#pragma unroll
    for (int nf = 0; nf < 4; ++nf) bcur[nf] = bnxt[nf];
  }

  float sc[4], bs[4];
#pragma unroll
  for (int nf = 0; nf < 4; ++nf) {
    sc[nf] = scale[nf * 16 + l16];
    bs[nf] = bias[nf * 16 + l16];
  }
#pragma unroll
  for (int mf = 0; mf < 2; ++mf) {
    const int oh = oh0 + wave * 2 + mf;
#pragma unroll
    for (int r = 0; r < 4; ++r) {
      const int ow = ow0 + quad * 4 + r;
      const size_t base = (((size_t)img * 112 + oh) * 112 + ow) * 64;
#pragma unroll
      for (int nf = 0; nf < 4; ++nf) {
        const float vv = fmaxf(acc[mf][nf][r] * sc[nf] + bs[nf], 0.f);
        yout[base + nf * 16 + l16] = f2bf(vv);
      }
    }
  }
}

// ---------------------------------------------------------------- conv3+pool
// Block = one 8x8 conv3 output tile x all 128 och (grid 49 x 64). Patch:
// 17x17x32 (one 32-ch half at a time) in parity-split seg-major LDS (19.6 KB
// -> 5 blocks/CU with launch_bounds(256,5)). Indexing verified in R8's fused
// kernel. Pool fused: fp32 tile sums -> shfl reduce -> 1 atomic/ch/block.
__global__ __launch_bounds__(256, 5) void conv3_pool(
    const unsigned short* __restrict__ act2,
    const unsigned short* __restrict__ bp3,
    const float* __restrict__ s3, const float* __restrict__ bb3,
    float* __restrict__ pooled) {
  __shared__ unsigned short c2p[4 * 17 * 18 * 8];  // 19584 B
  __shared__ float pbuf[128];
  const int t = threadIdx.x;
  const int img = blockIdx.y;
  const int ty = blockIdx.x / 7, tx = blockIdx.x % 7;
  const int o3h0 = ty * 8, o3w0 = tx * 8;
  const int wave = t >> 6, lane = t & 63, quad = lane >> 4, l16 = lane & 15;

  int a3off[4];
#pragma unroll
  for (int mf = 0; mf < 4; ++mf) {
    const int px = mf * 16 + l16;
    a3off[mf] = ((quad * 17 + (px >> 3) * 2) * 18 + (px & 7)) * 8;
  }

  floatx4 acc3[4][2];
#pragma unroll
  for (int mf = 0; mf < 4; ++mf) {
    acc3[mf][0] = (floatx4){0.f, 0.f, 0.f, 0.f};
    acc3[mf][1] = (floatx4){0.f, 0.f, 0.f, 0.f};
  }

  const int h0 = o3h0 * 2 - 1, w0 = o3w0 * 2 - 1;
#pragma unroll
  for (int h = 0; h < 2; ++h) {
    if (h) __syncthreads();  // previous half's reads done
    for (int c = t; c < 17 * 17 * 4; c += 256) {
      const int pix = c >> 2, seg = c & 3;
      const int pi = pix / 17, pj = pix % 17;
      const int ih = h0 + pi, iw = w0 + pj;
      uint4 v = make_uint4(0u, 0u, 0u, 0u);
      if ((unsigned)ih < 112u && (unsigned)iw < 112u)
        v = *(const uint4*)(act2 + (((size_t)img * 112 + ih) * 112 + iw) * 64 +
                            h * 32 + seg * 8);
      const int slot = (pj >> 1) + (pj & 1) * 9;  // parity split (stride 2)
      *(uint4*)(&c2p[((seg * 17 + pi) * 18 + slot) * 8]) = v;
    }
    __syncthreads();
#pragma unroll
    for (int tap = 0; tap < 9; ++tap) {
      const int kh = tap / 3, kw = tap % 3;
      const int kg = tap * 8 + h * 4 + quad;
      const short8 b0 = *(const short8*)(
          bp3 + ((size_t)kg * 128 + wave * 32 + l16) * 8);
      const short8 b1 = *(const short8*)(
          bp3 + ((size_t)kg * 128 + wave * 32 + 16 + l16) * 8);
      const int toff = (kh * 18 + (kw >> 1) + (kw & 1) * 9) * 8;
#pragma unroll
      for (int mf = 0; mf < 4; ++mf) {
        const short8 a = *(const short8*)(&c2p[a3off[mf] + toff]);
        acc3[mf][0] = __builtin_amdgcn_mfma_f32_16x16x32_bf16(a, b0,
                                                              acc3[mf][0], 0, 0, 0);
        acc3[mf][1] = __builtin_amdgcn_mfma_f32_16x16x32_bf16(a, b1,
                                                              acc3[mf][1], 0, 0, 0);
      }
    }
  }

  // ---- BN3 + ReLU + pool (waves own disjoint 32-ch slices)
#pragma unroll
  for (int nf = 0; nf < 2; ++nf) {
    const int ch = wave * 32 + nf * 16 + l16;
    const float sc = s3[ch], bs = bb3[ch];
    float s = 0.f;
#pragma unroll
    for (int mf = 0; mf < 4; ++mf)
#pragma unroll
      for (int r = 0; r < 4; ++r)
        s += fmaxf(acc3[mf][nf][r] * sc + bs, 0.f);
    s += __shfl_xor(s, 16);
    s += __shfl_xor(s, 32);
    if (lane < 16) pbuf[ch] = s;
  }
  __syncthreads();
  if (t < 128) atomicAdd(&pooled[(size_t)img * 128 + t], pbuf[t]);
}

// ---------------------------------------------------------------- linear
__global__ void linear_kernel(const float* __restrict__ pooled,
                              const float* __restrict__ ql,
                              const float* __restrict__ bl,
                              float* __restrict__ out) {
  const int idx = blockIdx.x * blockDim.x + threadIdx.x;
  if (idx >= 64 * 10) return;
  const int n = idx / 10, o = idx % 10;
  const float* p = pooled + (size_t)n * 128;
  const float* w = ql + (size_t)o * 128;
  float s = 0.f;
#pragma unroll 4
  for (int c = 0; c < 128; ++c) s += p[c] * w[c];
  out[idx] = s * (1.f / 3136.f) + bl[o];
}

// ---------------------------------------------------------------- launch
extern "C" void kernel_launch(void* const* d_in, const int* in_sizes, int n_in,
                              void* d_out, int out_size, void* d_ws,
                              size_t ws_size, hipStream_t stream) {
  const float* x  = (const float*)d_in[0];
  const float* w1 = (const float*)d_in[1];
  const float* g1 = (const float*)d_in[2];
  const float* b1 = (const float*)d_in[3];
  const float* m1 = (const float*)d_in[4];
  const float* v1 = (const float*)d_in[5];
  const float* w2 = (const float*)d_in[6];
  const float* g2 = (const float*)d_in[7];
  const float* b2 = (const float*)d_in[8];
  const float* m2 = (const float*)d_in[9];
  const float* v2 = (const float*)d_in[10];
  const float* w3 = (const float*)d_in[11];
  const float* g3 = (const float*)d_in[12];
  const float* b3 = (const float*)d_in[13];
  const float* m3 = (const float*)d_in[14];
  const float* v3 = (const float*)d_in[15];
  const float* wl = (const float*)d_in[16];
  const float* bl = (const float*)d_in[17];
  float* out = (float*)d_out;

  // ---- workspace layout ----
  float* Wf = (float*)d_ws;
  float* red = Wf;                // 16
  float* pooled = red + 16;       // 8192 (zeroed with red in one memset)
  float* q1t = pooled + 8192;     // 864
  float* ql = q1t + 864;          // 1280
  float* s1 = ql + 1280;  float* bb1 = s1 + 32;
  float* s2 = bb1 + 32;   float* bb2 = s2 + 64;
  float* s3 = bb2 + 64;   float* bb3 = s3 + 128;
  unsigned short* Us = (unsigned short*)(bb3 + 128);
  unsigned short* bp2 = Us;                 // 288*64   = 18432
  unsigned short* bp3 = bp2 + 18432;        // 576*128  = 73728
  unsigned short* act1 = bp3 + 73728;       // 64*12544*32 = 25690112
  unsigned short* act2 = act1 + 25690112;   // 64*12544*64 = 51380224
  // total ~155 MB < ws_size

  // ---- prep: memset + 2 reduction phases + one merged pack/fold kernel ----
  hipMemsetAsync(red, 0, (16 + 8192) * sizeof(float), stream);
  tern_phase1<<<dim3(288, 4), 256, 0, stream>>>(w1, w2, w3, wl, 864, 18432,
                                                73728, 1280, red);
  tern_phase2<<<dim3(288, 4), 256, 0, stream>>>(w1, w2, w3, wl, 864, 18432,
                                                73728, 1280, red);
  prep_all<<<370, 256, 0, stream>>>(w1, w2, w3, wl, g1, b1, m1, v1, g2, b2,
                                    m2, v2, g3, b3, m3, v3, red, q1t, ql, s1,
                                    bb1, s2, bb2, s3, bb3, bp2, bp3);

  // ---- network ----
  conv1_v2<<<dim3(56, 64), 256, 0, stream>>>(x, q1t, s1, bb1, act1);
  conv2_halo<<<dim3(98, 1, 64), 256, 0, stream>>>(act1, bp2, s2, bb2, act2);
  conv3_pool<<<dim3(49, 64), 256, 0, stream>>>(act2, bp3, s3, bb3, pooled);
  linear_kernel<<<3, 256, 0, stream>>>(pooled, ql, bl, out);
}